// Round 5
// baseline (138.536 us; speedup 1.0000x reference)
//
#include <hip/hip_runtime.h>

// B=4, T=4096, E=1024, H=64.
// out = Q @ M_b,  M_b = (1/32) * K_b^T V_b,  Q/K/V = idx@W + b   (linear attention:
// reference applies no mask/softmax). Scale folded into Wk/bk.
//
// R12 = R11 with the B-slot pipeline hazard fixed. R11 bug: bE/bO were refilled
// (kk+2 weights) BEFORE the MFMAs consuming them -> 30/32 K-steps used wrong W.
// Fix: capture current B frags into SSA locals before issuing refill loads.
// Structure: no LDS staging for A -- MFMA A-fragments load directly from global
// (2x dwordx4/lane, 128B-contiguous per row), converted in-register with
// v_cvt_pk_bf16_f32. A and B 2-deep in named even/odd slots, no barriers in main
// loop. 4 waves duplicate A loads; L2 absorbs (HBM still 64MB). LDS 13.6KB.

typedef __attribute__((ext_vector_type(8))) short bf16x8;   // 8 bf16 = 4 VGPRs
typedef __attribute__((ext_vector_type(4))) float f32x4;    // MFMA C/D

#define MFMA16(a, b, c) __builtin_amdgcn_mfma_f32_16x16x32_bf16((a), (b), (c), 0, 0, 0)

__device__ __forceinline__ unsigned short f2bf(float f) {
    unsigned int u = __float_as_uint(f);
    u += 0x7fffu + ((u >> 16) & 1u);          // round-to-nearest-even
    return (unsigned short)(u >> 16);
}

__device__ __forceinline__ unsigned int cvtpk(float a, float b) {
    unsigned int r;                           // r = {bf16(a) lo, bf16(b) hi}
    asm("v_cvt_pk_bf16_f32 %0, %1, %2" : "=v"(r) : "v"(a), "v"(b));
    return r;
}

__device__ __forceinline__ bf16x8 cvt8(float4 lo, float4 hi) {
    union { unsigned int u[4]; bf16x8 v; } r;
    r.u[0] = cvtpk(lo.x, lo.y);
    r.u[1] = cvtpk(lo.z, lo.w);
    r.u[2] = cvtpk(hi.x, hi.y);
    r.u[3] = cvtpk(hi.z, hi.w);
    return r.v;
}

// ---------------------------------------------------------------------------
// K0: weights -> MFMA-fragment order; zero the 8-way Mf accumulator (ws poisoned).
// Chunk t = (kk*12 + nt)*64 + lane holds 8 bf16:
//   W^T[n][k], n = nt*16 + (lane&15), k = kk*32 + (lane>>4)*8 + j.
// n<64 -> Wq, n<128 -> Wk * 1/32, else Wv.   (W is [k][h] in memory)
__global__ void prep(const float* __restrict__ Wq, const float* __restrict__ Wk,
                     const float* __restrict__ Wv, unsigned short* __restrict__ WB,
                     float* __restrict__ Mf8) {
    int t = blockIdx.x * 256 + threadIdx.x;   // 96 blocks -> 24576 chunks
    for (int z = t; z < 131072; z += 24576) Mf8[z] = 0.f;   // 8*4*64*64 fp32
    int kki = t / 768;
    int rem = t - kki * 768;
    int nt = rem >> 6, lane = rem & 63;
    int n = nt * 16 + (lane & 15);
    int kb = kki * 32 + ((lane >> 4) * 8);
    int mm = n >> 6, h = n & 63;
    const float* W = (mm == 0) ? Wq : (mm == 1) ? Wk : Wv;
    float sc = (mm == 1) ? 0.03125f : 1.0f;
    bf16x8 v;
    #pragma unroll
    for (int j = 0; j < 8; j++) v[j] = (short)f2bf(W[(size_t)(kb + j) * 64 + h] * sc);
    *(bf16x8*)(WB + (size_t)t * 8) = v;
}

// ---------------------------------------------------------------------------
// K1: fused QKV projection + local K^T V contribution. Block = 32 rows, 4 waves,
// grid 512. Main loop: per kk, 4 A dwordx4 direct from idx (even/odd slots,
// refilled 2 kk ahead) + cvt_pk to bf16 + 3 B 16B loads from L2-hot WB (even/odd
// slots, 2 ahead) + 6 MFMAs. No LDS, no barriers until epilogue.
__global__ __launch_bounds__(256, 3) void qkv_m(
    const float* __restrict__ idx, const unsigned short* __restrict__ WB,
    const float* __restrict__ bq, const float* __restrict__ bk, const float* __restrict__ bv,
    unsigned short* __restrict__ Q, float* __restrict__ Mf8) {
    __shared__ unsigned short Lq[32 * 68];     // 4352 B
    __shared__ unsigned short Lk[64 * 36];     // 4608 B, K local [h][t]
    __shared__ unsigned short Lv[64 * 36];     // 4608 B, V local [h][t]

    const int tid = threadIdx.x, lane = tid & 63, w = tid >> 6;
    const int r0 = blockIdx.x * 32;

    // A base pointers: lane l covers row r0+(l&15) (+16 for frag 1), k-offset (l>>4)*8
    const float* A0 = idx + (size_t)(r0 + (lane & 15)) * 1024 + ((lane >> 4) * 8);
    const float* A1 = A0 + 16 * 1024;

    // ---- prologue: preload kk=0 (even slot) and kk=1 (odd slot) ----
    float4 aA0 = *(const float4*)(A0 + 0),  aA1 = *(const float4*)(A0 + 4);
    float4 aA2 = *(const float4*)(A1 + 0),  aA3 = *(const float4*)(A1 + 4);
    float4 aB0 = *(const float4*)(A0 + 32), aB1 = *(const float4*)(A0 + 36);
    float4 aB2 = *(const float4*)(A1 + 32), aB3 = *(const float4*)(A1 + 36);
    bf16x8 bE[3], bO[3];
    {
        const unsigned short* Bp0 = WB + (size_t)(lane * 8);              // kk=0
        const unsigned short* Bp1 = WB + (size_t)(12 * 64 + lane) * 8;    // kk=1
        #pragma unroll
        for (int j = 0; j < 3; j++) {
            bE[j] = *(const bf16x8*)(Bp0 + (w + j * 4) * 512);
            bO[j] = *(const bf16x8*)(Bp1 + (w + j * 4) * 512);
        }
    }

    const f32x4 z4 = {0.f, 0.f, 0.f, 0.f};
    f32x4 acc[2][3] = {{z4, z4, z4}, {z4, z4, z4}};

    for (int kk2 = 0; kk2 < 32; kk2 += 2) {
        // ---- even kk = kk2: capture current A/B, refill for kk2+2, then MFMA ----
        {
            bf16x8 a0 = cvt8(aA0, aA1), a1 = cvt8(aA2, aA3);
            bf16x8 bu0 = bE[0], bu1 = bE[1], bu2 = bE[2];   // capture BEFORE refill
            if (kk2 < 30) {
                const float* p0 = A0 + (kk2 + 2) * 32;
                const float* p1 = A1 + (kk2 + 2) * 32;
                aA0 = *(const float4*)p0; aA1 = *(const float4*)(p0 + 4);
                aA2 = *(const float4*)p1; aA3 = *(const float4*)(p1 + 4);
                const unsigned short* Bp = WB + (size_t)(((kk2 + 2) * 12) * 64 + lane) * 8;
                #pragma unroll
                for (int j = 0; j < 3; j++) bE[j] = *(const bf16x8*)(Bp + (w + j * 4) * 512);
            }
            acc[0][0] = MFMA16(a0, bu0, acc[0][0]);
            acc[1][0] = MFMA16(a1, bu0, acc[1][0]);
            acc[0][1] = MFMA16(a0, bu1, acc[0][1]);
            acc[1][1] = MFMA16(a1, bu1, acc[1][1]);
            acc[0][2] = MFMA16(a0, bu2, acc[0][2]);
            acc[1][2] = MFMA16(a1, bu2, acc[1][2]);
        }
        // ---- odd kk = kk2+1: capture, refill for kk2+3, then MFMA ----
        {
            bf16x8 a0 = cvt8(aB0, aB1), a1 = cvt8(aB2, aB3);
            bf16x8 bu0 = bO[0], bu1 = bO[1], bu2 = bO[2];   // capture BEFORE refill
            if (kk2 < 30) {
                const float* p0 = A0 + (kk2 + 3) * 32;
                const float* p1 = A1 + (kk2 + 3) * 32;
                aB0 = *(const float4*)p0; aB1 = *(const float4*)(p0 + 4);
                aB2 = *(const float4*)p1; aB3 = *(const float4*)(p1 + 4);
                const unsigned short* Bp = WB + (size_t)(((kk2 + 3) * 12) * 64 + lane) * 8;
                #pragma unroll
                for (int j = 0; j < 3; j++) bO[j] = *(const bf16x8*)(Bp + (w + j * 4) * 512);
            }
            acc[0][0] = MFMA16(a0, bu0, acc[0][0]);
            acc[1][0] = MFMA16(a1, bu0, acc[1][0]);
            acc[0][1] = MFMA16(a0, bu1, acc[0][1]);
            acc[1][1] = MFMA16(a1, bu1, acc[1][1]);
            acc[0][2] = MFMA16(a0, bu2, acc[0][2]);
            acc[1][2] = MFMA16(a1, bu2, acc[1][2]);
        }
    }

    // ---- epilogue: bias + Q/K/V into LDS ----
    {
        const int h     = w * 16 + (lane & 15);
        const int rbase = (lane >> 4) * 4;
        float bias0 = bq[h], bias1 = bk[h] * 0.03125f, bias2 = bv[h];
        #pragma unroll
        for (int rf = 0; rf < 2; rf++) {
            #pragma unroll
            for (int reg = 0; reg < 4; reg++) {
                int r = rf * 16 + rbase + reg;
                Lq[r * 68 + h] = f2bf(acc[rf][0][reg] + bias0);
                Lk[h * 36 + r] = f2bf(acc[rf][1][reg] + bias1);   // [h][t], pad 36
                Lv[h * 36 + r] = f2bf(acc[rf][2][reg] + bias2);
            }
        }
    }
    __syncthreads();

    // ---- Q to global, coalesced 16B/lane ----
    {
        int qr = tid >> 3, qh = (tid & 7) * 8;
        *(uint4*)(Q + (size_t)(r0 + qr) * 64 + qh) = *(const uint4*)(Lq + qr * 68 + qh);
    }

    // ---- M contribution (K=t=32) + 8-way-split atomicAdd ----
    {
        const int tq = (lane >> 4) * 8;
        bf16x8 a = *(const bf16x8*)&Lk[(16 * w + (lane & 15)) * 36 + tq];
        const f32x4 z4b = {0.f, 0.f, 0.f, 0.f};
        f32x4 accM[4];
        #pragma unroll
        for (int nt = 0; nt < 4; nt++) {
            bf16x8 bb = *(const bf16x8*)&Lv[(nt * 16 + (lane & 15)) * 36 + tq];
            accM[nt] = MFMA16(a, bb, z4b);
        }
        float* P = Mf8 + (((size_t)(blockIdx.x & 7) * 4) + (size_t)(r0 >> 12)) * 4096;
        const int rowb = 16 * w + (lane >> 4) * 4;
        #pragma unroll
        for (int nt = 0; nt < 4; nt++)
            #pragma unroll
            for (int reg = 0; reg < 4; reg++)
                atomicAdd(&P[(rowb + reg) * 64 + nt * 16 + (lane & 15)], accM[nt][reg]);
    }
}

// ---------------------------------------------------------------------------
// K2: out[r][h2] = Q[r][:] @ M_b[:, h2], fp32 out. Sums the 8 Mf copies (L2-hot),
// converts to bf16 fragments in LDS (transposed [h2][h1], stride 72: 2-way banks).
__global__ __launch_bounds__(256) void qm(
    const unsigned short* __restrict__ Q, const float* __restrict__ Mf8,
    float* __restrict__ out) {
    __shared__ unsigned short Lm[64 * 72];
    const int lane = threadIdx.x & 63, wave = threadIdx.x >> 6;
    const int r0 = blockIdx.x * 64;
    const int b  = r0 >> 12;
    {
        const int tt = threadIdx.x;
        int h1 = tt >> 2, h2c = (tt & 3) * 16;
        const float* Mp = Mf8 + (size_t)b * 4096 + h1 * 64 + h2c;
        float vals[16];
        #pragma unroll
        for (int u = 0; u < 16; u += 4) *(float4*)(vals + u) = *(const float4*)(Mp + u);
        #pragma unroll
        for (int c = 1; c < 8; c++) {
            const float* Mc = Mp + (size_t)c * 16384;   // copy stride = 4*4096 floats
            #pragma unroll
            for (int u = 0; u < 16; u += 4) {
                float4 t = *(const float4*)(Mc + u);
                vals[u] += t.x; vals[u + 1] += t.y; vals[u + 2] += t.z; vals[u + 3] += t.w;
            }
        }
        #pragma unroll
        for (int u = 0; u < 16; u++) Lm[(h2c + u) * 72 + h1] = f2bf(vals[u]);
    }
    __syncthreads();
    const f32x4 z4 = {0.f, 0.f, 0.f, 0.f};
    f32x4 acc[4] = {z4, z4, z4, z4};
    const int rr = r0 + 16 * wave + (lane & 15);
    const int kq = (lane >> 4) * 8;
    #pragma unroll
    for (int ks = 0; ks < 2; ks++) {
        int k0 = ks * 32;
        bf16x8 a = *(const bf16x8*)&Q[(size_t)rr * 64 + k0 + kq];
        #pragma unroll
        for (int nt = 0; nt < 4; nt++) {
            bf16x8 bb = *(const bf16x8*)&Lm[(size_t)(nt * 16 + (lane & 15)) * 72 + k0 + kq];
            acc[nt] = MFMA16(a, bb, acc[nt]);
        }
    }
    const int rowb = r0 + 16 * wave + (lane >> 4) * 4;
    #pragma unroll
    for (int nt = 0; nt < 4; nt++)
        #pragma unroll
        for (int reg = 0; reg < 4; reg++)
            out[(size_t)(rowb + reg) * 64 + nt * 16 + (lane & 15)] = acc[nt][reg];
}

// ---------------------------------------------------------------------------
// Workspace layout:
//   [0, 384K)         WB
//   [1M, 1M+512K)     Mf8 (8 copies x 4 batches x 4096 fp32, zeroed by prep)
//   [2M, 4M)          Q
extern "C" void kernel_launch(void* const* d_in, const int* in_sizes, int n_in,
                              void* d_out, int out_size, void* d_ws, size_t ws_size,
                              hipStream_t stream) {
    const float* idx = (const float*)d_in[0];
    const float* Wq  = (const float*)d_in[1];
    const float* bq  = (const float*)d_in[2];
    const float* Wk  = (const float*)d_in[3];
    const float* bk  = (const float*)d_in[4];
    const float* Wv  = (const float*)d_in[5];
    const float* bv  = (const float*)d_in[6];
    float* out = (float*)d_out;

    char* ws = (char*)d_ws;
    unsigned short* WB  = (unsigned short*)(ws);
    float*          Mf8 = (float*)(ws + (1024u << 10));
    unsigned short* Q   = (unsigned short*)(ws + (2048u << 10));

    hipLaunchKernelGGL(prep,  dim3(96),  dim3(256), 0, stream, Wq, Wk, Wv, WB, Mf8);
    hipLaunchKernelGGL(qkv_m, dim3(512), dim3(256), 0, stream,
                       idx, WB, bq, bk, bv, Q, Mf8);
    hipLaunchKernelGGL(qm,    dim3(256), dim3(256), 0, stream, Q, Mf8, out);
}